// Round 17
// baseline (268.055 us; speedup 1.0000x reference)
//
#include <hip/hip_runtime.h>
#include <hip/hip_bf16.h>
#include <hip/hip_fp16.h>

#define N_NODES 50000
#define N_EDGES 800000
#define DIM 64
#define ODIM 32
#define N_GRAPHS 512
#define SCAN_NB ((N_NODES + 255) / 256)   // 196
#define NXCD 8
#define DST_RANGE ((N_NODES + NXCD - 1) / NXCD)   // 6250

__device__ __forceinline__ float bflo(unsigned int u) { return __uint_as_float(u << 16); }
__device__ __forceinline__ float bfhi(unsigned int u) { return __uint_as_float(u & 0xffff0000u); }
__device__ __forceinline__ float h16tof(unsigned int hbits) {
    return __half2float(__ushort_as_half((unsigned short)hbits));
}

// ---- graph prep: counting-sort edges by dst into CSR ----

__global__ void count_deg(const int* __restrict__ dst, int* __restrict__ cnt) {
    int e = blockIdx.x * blockDim.x + threadIdx.x;
    if (e < N_EDGES) atomicAdd(&cnt[__builtin_nontemporal_load(&dst[e])], 1);
}

// ---- 2-phase exclusive scan over cnt[N_NODES] ----

__global__ __launch_bounds__(256) void scan_p1(const int* __restrict__ cnt,
                                               int* __restrict__ blocksum) {
    __shared__ int ws[4];
    int i = blockIdx.x * 256 + threadIdx.x;
    int v = (i < N_NODES) ? cnt[i] : 0;
    for (int d = 32; d > 0; d >>= 1) v += __shfl_down(v, d, 64);
    int lane = threadIdx.x & 63, wid = threadIdx.x >> 6;
    if (lane == 0) ws[wid] = v;
    __syncthreads();
    if (threadIdx.x == 0) blocksum[blockIdx.x] = ws[0] + ws[1] + ws[2] + ws[3];
}

__global__ __launch_bounds__(256) void scan_p3(const int* __restrict__ cnt,
                                               const int* __restrict__ blocksum,
                                               int* __restrict__ off,
                                               int* __restrict__ cursor,
                                               float* __restrict__ inv_sqrt,
                                               float* __restrict__ invdeg) {
    __shared__ int wtot[4];
    __shared__ int bb[SCAN_NB + 1];
    {
        int t = threadIdx.x;
        int v = (t < SCAN_NB) ? blocksum[t] : 0;
        int lane = t & 63, wid = t >> 6;
        int incl = v;
        for (int d = 1; d < 64; d <<= 1) {
            int u = __shfl_up(incl, d, 64);
            if (lane >= d) incl += u;
        }
        if (lane == 63) wtot[wid] = incl;
        __syncthreads();
        int base = 0;
        for (int w = 0; w < wid; ++w) base += wtot[w];
        incl += base;
        if (t <= SCAN_NB) bb[t] = incl - v;   // exclusive; bb[SCAN_NB] = total
        __syncthreads();
    }
    if (blockIdx.x == 0 && threadIdx.x == 0) off[N_NODES] = bb[SCAN_NB];
    __syncthreads();

    int i = blockIdx.x * 256 + threadIdx.x;
    int v = (i < N_NODES) ? cnt[i] : 0;
    int lane = threadIdx.x & 63, wid = threadIdx.x >> 6;
    int incl = v;
    for (int d = 1; d < 64; d <<= 1) {
        int u = __shfl_up(incl, d, 64);
        if (lane >= d) incl += u;
    }
    __syncthreads();
    if (lane == 63) wtot[wid] = incl;
    __syncthreads();
    int base = bb[blockIdx.x];
    for (int w = 0; w < wid; ++w) base += wtot[w];
    int excl = base + incl - v;
    if (i < N_NODES) {
        off[i] = excl; cursor[i] = excl;
        float d = (float)(v + 1);   // self-loop
        inv_sqrt[i] = rsqrtf(d);
        invdeg[i]   = 1.0f / d;
    }
}

// XCD-partitioned scatter: block = (chunk, range); blockIdx%8 -> XCD round-robin.
// Edge record packed to 4B: src (u16) | half(w) << 16.
__global__ void scatter_edges(const int* __restrict__ src, const int* __restrict__ dst,
                              const float* __restrict__ inv_sqrt,
                              int* __restrict__ cursor,
                              unsigned int* __restrict__ edges) {
    int chunk = blockIdx.x >> 3;
    int range = blockIdx.x & 7;
    int e = chunk * 256 + threadIdx.x;
    if (e >= N_EDGES) return;
    int d = dst[e];
    int lo = range * DST_RANGE;
    if ((unsigned)(d - lo) < (unsigned)DST_RANGE) {
        int s = src[e];
        int pos = atomicAdd(&cursor[d], 1);
        float w = inv_sqrt[s] * inv_sqrt[d];
        unsigned short hw = __half_as_ushort(__float2half(w));
        edges[pos] = (unsigned int)s | ((unsigned int)hw << 16);
    }
}

// ---- quarter-wave packed merged-stream gather for 4 consecutive nodes ----
// H viewed as uint2 rows of 16 (4 bf16 per uint2). Lane = (m=j&15, q=j>>4):
// quarter q handles edges k+4i+q; one uint2 gather serves 4 edges/wave-inst.
// acc[r] = float4 partial sums of columns 4m..4m+3 for node n0+r (this quarter).
// Caller combines quarters via shfl_xor(16)+shfl_xor(32).
__device__ __forceinline__ void gather4_q(
    const uint2* __restrict__ H4,
    const unsigned int* __restrict__ edges,
    int e0, int b1, int b2, int b3, int e4, int m, int q,
    float4 (&acc)[4])
{
    int k = e0;
    int B = (e4 - e0) >> 3;

    unsigned int Ec[2]; uint2 Uc[2];
    unsigned int En[2];

    auto ld2 = [&](unsigned int* E, int kb) {
        E[0] = edges[kb + q];
        E[1] = edges[kb + 4 + q];
    };
    auto gt2 = [&](uint2* U, const unsigned int* E) {
        U[0] = H4[(size_t)(E[0] & 0xffffu) * 16 + m];
        U[1] = H4[(size_t)(E[1] & 0xffffu) * 16 + m];
    };
    auto consume = [&](const unsigned int* E, const uint2* U, int kb) {
        int selA = (kb >= b1) + (kb >= b2) + (kb >= b3);
        int selB = (kb + 7 >= b1) + (kb + 7 >= b2) + (kb + 7 >= b3);
        if (selA == selB) {                 // whole batch in one node (common)
            float s0 = 0.f, s1 = 0.f, s2 = 0.f, s3 = 0.f;
#pragma unroll
            for (int i = 0; i < 2; ++i) {
                float w = h16tof(E[i] >> 16);
                s0 = fmaf(bflo(U[i].x), w, s0);
                s1 = fmaf(bfhi(U[i].x), w, s1);
                s2 = fmaf(bflo(U[i].y), w, s2);
                s3 = fmaf(bfhi(U[i].y), w, s3);
            }
            if      (selA == 0) { acc[0].x += s0; acc[0].y += s1; acc[0].z += s2; acc[0].w += s3; }
            else if (selA == 1) { acc[1].x += s0; acc[1].y += s1; acc[1].z += s2; acc[1].w += s3; }
            else if (selA == 2) { acc[2].x += s0; acc[2].y += s1; acc[2].z += s2; acc[2].w += s3; }
            else                { acc[3].x += s0; acc[3].y += s1; acc[3].z += s2; acc[3].w += s3; }
        } else {                            // boundary batch: per-edge select
#pragma unroll
            for (int i = 0; i < 2; ++i) {
                int kk = kb + 4 * i + q;
                float w = h16tof(E[i] >> 16);
                float p0 = bflo(U[i].x) * w;
                float p1 = bfhi(U[i].x) * w;
                float p2 = bflo(U[i].y) * w;
                float p3 = bfhi(U[i].y) * w;
                int sel = (kk >= b1) + (kk >= b2) + (kk >= b3);
#pragma unroll
                for (int r = 0; r < 4; ++r) {
                    acc[r].x += (sel == r) ? p0 : 0.f;
                    acc[r].y += (sel == r) ? p1 : 0.f;
                    acc[r].z += (sel == r) ? p2 : 0.f;
                    acc[r].w += (sel == r) ? p3 : 0.f;
                }
            }
        }
    };

    if (B >= 2) {
        ld2(Ec, k);
        gt2(Uc, Ec);
        ld2(En, k + 8);
        for (int b = 0; b < B - 2; ++b) {
            uint2 Un[2];
            gt2(Un, En);          // gathers batch b+1 in flight
            unsigned int Ef[2];
            ld2(Ef, k + 16);      // edge loads batch b+2 in flight
            consume(Ec, Uc, k);   // waits only on batch b gathers
#pragma unroll
            for (int i = 0; i < 2; ++i) { Ec[i] = En[i]; Uc[i] = Un[i]; En[i] = Ef[i]; }
            k += 8;
        }
        {
            uint2 Un[2];
            gt2(Un, En);
            consume(Ec, Uc, k);
#pragma unroll
            for (int i = 0; i < 2; ++i) { Ec[i] = En[i]; Uc[i] = Un[i]; }
            k += 8;
            consume(Ec, Uc, k);
            k += 8;
        }
    } else if (B == 1) {
        ld2(Ec, k); gt2(Uc, Ec); consume(Ec, Uc, k); k += 8;
    }
    for (; k < e4; ++k) {
        if ((k & 3) == q) {       // split tail edges between quarters
            unsigned int e = edges[k];
            uint2 u = H4[(size_t)(e & 0xffffu) * 16 + m];
            float w = h16tof(e >> 16);
            float p0 = bflo(u.x) * w, p1 = bfhi(u.x) * w;
            float p2 = bflo(u.y) * w, p3 = bfhi(u.y) * w;
            int sel = (k >= b1) + (k >= b2) + (k >= b3);
#pragma unroll
            for (int r = 0; r < 4; ++r) {
                acc[r].x += (sel == r) ? p0 : 0.f;
                acc[r].y += (sel == r) ? p1 : 0.f;
                acc[r].z += (sel == r) ? p2 : 0.f;
                acc[r].w += (sel == r) ? p3 : 0.f;
            }
        }
    }
}

// combine quarters: after this every lane holds full sums
__device__ __forceinline__ void combine_quarters(float4 (&acc)[4]) {
#pragma unroll
    for (int r = 0; r < 4; ++r) {
        acc[r].x += __shfl_xor(acc[r].x, 16); acc[r].y += __shfl_xor(acc[r].y, 16);
        acc[r].z += __shfl_xor(acc[r].z, 16); acc[r].w += __shfl_xor(acc[r].w, 16);
        acc[r].x += __shfl_xor(acc[r].x, 32); acc[r].y += __shfl_xor(acc[r].y, 32);
        acc[r].z += __shfl_xor(acc[r].z, 32); acc[r].w += __shfl_xor(acc[r].w, 32);
    }
}

// ---- h = X @ W  (N x 64 @ 64 x 64); bf16 output only ----

__global__ __launch_bounds__(256) void gemm64(const float* __restrict__ X,
                                              const float* __restrict__ W,
                                              __hip_bfloat16* __restrict__ Ybf,
                                              int nrows) {
    __shared__ float Ws[64 * 64];
    for (int i = threadIdx.x; i < 64 * 64; i += 256) Ws[i] = W[i];
    __syncthreads();
    int wave = threadIdx.x >> 6;
    int j    = threadIdx.x & 63;
    int row0 = (blockIdx.x * 4 + wave) * 8;
    if (row0 >= nrows) return;
    float acc[8] = {0,0,0,0,0,0,0,0};
    const float* x0 = X + (size_t)row0 * DIM;   // wave-uniform
    int nr = (row0 + 8 <= nrows) ? 8 : (nrows - row0);
    if (nr == 8) {
#pragma unroll
        for (int k4 = 0; k4 < 16; ++k4) {
            float w0 = Ws[(4 * k4 + 0) * 64 + j];
            float w1 = Ws[(4 * k4 + 1) * 64 + j];
            float w2 = Ws[(4 * k4 + 2) * 64 + j];
            float w3 = Ws[(4 * k4 + 3) * 64 + j];
#pragma unroll
            for (int r = 0; r < 8; ++r) {
                float4 x4 = *(const float4*)&x0[r * DIM + k4 * 4];
                acc[r] = fmaf(x4.x, w0, acc[r]);
                acc[r] = fmaf(x4.y, w1, acc[r]);
                acc[r] = fmaf(x4.z, w2, acc[r]);
                acc[r] = fmaf(x4.w, w3, acc[r]);
            }
        }
    } else {
        for (int k4 = 0; k4 < 16; ++k4) {
            float w0 = Ws[(4 * k4 + 0) * 64 + j];
            float w1 = Ws[(4 * k4 + 1) * 64 + j];
            float w2 = Ws[(4 * k4 + 2) * 64 + j];
            float w3 = Ws[(4 * k4 + 3) * 64 + j];
            for (int r = 0; r < nr; ++r) {
                float4 x4 = *(const float4*)&x0[r * DIM + k4 * 4];
                acc[r] = fmaf(x4.x, w0, acc[r]);
                acc[r] = fmaf(x4.y, w1, acc[r]);
                acc[r] = fmaf(x4.z, w2, acc[r]);
                acc[r] = fmaf(x4.w, w3, acc[r]);
            }
        }
    }
    for (int r = 0; r < nr; ++r)
        Ybf[(size_t)(row0 + r) * DIM + j] = __float2bfloat16(acc[r]);
}

// ---- fused: layer-1 aggregate (+bias1, relu) THEN layer-2 gemm (@W2) ----

__global__ __launch_bounds__(256) void agg_gemm(const __hip_bfloat16* __restrict__ Hbf,
                                                const int* __restrict__ off,
                                                const unsigned int* __restrict__ edges,
                                                const float* __restrict__ invdeg,
                                                const float* __restrict__ bias,
                                                const float* __restrict__ W2,
                                                __hip_bfloat16* __restrict__ Ybf2) {
    __shared__ float Ws[64 * 64];
    __shared__ float rowbuf[4][4][64];   // [wave][r][j]
    for (int i = threadIdx.x; i < 64 * 64; i += 256) Ws[i] = W2[i];
    __syncthreads();
    const uint2* H4 = (const uint2*)Hbf;
    int wave = threadIdx.x >> 6;
    int j    = threadIdx.x & 63;
    int m = j & 15, q = j >> 4;
    int n0   = (blockIdx.x * 4 + wave) * 4;   // N_NODES = 16*3125: exact
    int e0 = off[n0], b1v = off[n0 + 1], b2v = off[n0 + 2], b3v = off[n0 + 3], e4 = off[n0 + 4];
    float4 acc[4] = {{0,0,0,0},{0,0,0,0},{0,0,0,0},{0,0,0,0}};
    gather4_q(H4, edges, e0, b1v, b2v, b3v, e4, m, q, acc);
    combine_quarters(acc);
    float bb0 = bias[4 * m], bb1 = bias[4 * m + 1], bb2 = bias[4 * m + 2], bb3 = bias[4 * m + 3];
#pragma unroll
    for (int r = 0; r < 4; ++r) {
        uint2 u = H4[(size_t)(n0 + r) * 16 + m];   // self row (broadcast)
        float iv = invdeg[n0 + r];
        float v0 = fmaf(bflo(u.x), iv, acc[r].x) + bb0;
        float v1 = fmaf(bfhi(u.x), iv, acc[r].y) + bb1;
        float v2 = fmaf(bflo(u.y), iv, acc[r].z) + bb2;
        float v3 = fmaf(bfhi(u.y), iv, acc[r].w) + bb3;
        if (q == 0) {
            float4 st = make_float4(fmaxf(v0, 0.f), fmaxf(v1, 0.f),
                                    fmaxf(v2, 0.f), fmaxf(v3, 0.f));
            *(float4*)&rowbuf[wave][r][4 * m] = st;
        }
    }
    // same-wave LDS write->read: compiler inserts lgkmcnt wait; no barrier needed
    float acc2[4] = {0.f, 0.f, 0.f, 0.f};
#pragma unroll
    for (int k4 = 0; k4 < 16; ++k4) {
        float w0 = Ws[(4 * k4 + 0) * 64 + j];
        float w1 = Ws[(4 * k4 + 1) * 64 + j];
        float w2 = Ws[(4 * k4 + 2) * 64 + j];
        float w3 = Ws[(4 * k4 + 3) * 64 + j];
#pragma unroll
        for (int r = 0; r < 4; ++r) {
            float4 h4 = *(const float4*)&rowbuf[wave][r][k4 * 4];  // broadcast: free
            acc2[r] = fmaf(h4.x, w0, acc2[r]);
            acc2[r] = fmaf(h4.y, w1, acc2[r]);
            acc2[r] = fmaf(h4.z, w2, acc2[r]);
            acc2[r] = fmaf(h4.w, w3, acc2[r]);
        }
    }
#pragma unroll
    for (int r = 0; r < 4; ++r)
        Ybf2[(size_t)(n0 + r) * DIM + j] = __float2bfloat16(acc2[r]);
}

// ---- layer-2 aggregate (+bias2, relu) fused with mean-pool accumulation ----

__global__ __launch_bounds__(256) void agg_pool(const __hip_bfloat16* __restrict__ Hbf,
                                                const int* __restrict__ off,
                                                const unsigned int* __restrict__ edges,
                                                const float* __restrict__ invdeg,
                                                const float* __restrict__ bias,
                                                const int* __restrict__ batch,
                                                float* __restrict__ sums) {
    const uint2* H4 = (const uint2*)Hbf;
    int wave = threadIdx.x >> 6;
    int j    = threadIdx.x & 63;
    int m = j & 15, q = j >> 4;
    int n0   = (blockIdx.x * 4 + wave) * 4;   // exact
    int e0 = off[n0], b1v = off[n0 + 1], b2v = off[n0 + 2], b3v = off[n0 + 3], e4 = off[n0 + 4];
    float4 acc[4] = {{0,0,0,0},{0,0,0,0},{0,0,0,0},{0,0,0,0}};
    gather4_q(H4, edges, e0, b1v, b2v, b3v, e4, m, q, acc);
    combine_quarters(acc);
    float bb0 = bias[4 * m], bb1 = bias[4 * m + 1], bb2 = bias[4 * m + 2], bb3 = bias[4 * m + 3];
    float4 vv[4];
#pragma unroll
    for (int r = 0; r < 4; ++r) {
        uint2 u = H4[(size_t)(n0 + r) * 16 + m];
        float iv = invdeg[n0 + r];
        vv[r].x = fmaxf(fmaf(bflo(u.x), iv, acc[r].x) + bb0, 0.f);
        vv[r].y = fmaxf(fmaf(bfhi(u.x), iv, acc[r].y) + bb1, 0.f);
        vv[r].z = fmaxf(fmaf(bflo(u.y), iv, acc[r].z) + bb2, 0.f);
        vv[r].w = fmaxf(fmaf(bfhi(u.y), iv, acc[r].w) + bb3, 0.f);
    }
    if (q == 0) {
        int g0 = batch[n0], g3 = batch[n0 + 3];
        if (g0 == g3) {
            float4 t;
            t.x = (vv[0].x + vv[1].x) + (vv[2].x + vv[3].x);
            t.y = (vv[0].y + vv[1].y) + (vv[2].y + vv[3].y);
            t.z = (vv[0].z + vv[1].z) + (vv[2].z + vv[3].z);
            t.w = (vv[0].w + vv[1].w) + (vv[2].w + vv[3].w);
            atomicAdd(&sums[g0 * DIM + 4 * m + 0], t.x);
            atomicAdd(&sums[g0 * DIM + 4 * m + 1], t.y);
            atomicAdd(&sums[g0 * DIM + 4 * m + 2], t.z);
            atomicAdd(&sums[g0 * DIM + 4 * m + 3], t.w);
        } else {
#pragma unroll
            for (int r = 0; r < 4; ++r) {
                int g = batch[n0 + r];
                atomicAdd(&sums[g * DIM + 4 * m + 0], vv[r].x);
                atomicAdd(&sums[g * DIM + 4 * m + 1], vv[r].y);
                atomicAdd(&sums[g * DIM + 4 * m + 2], vv[r].z);
                atomicAdd(&sums[g * DIM + 4 * m + 3], vv[r].w);
            }
        }
    }
}

// ---- FC over pooled means: one 64-thread block per graph ----

__global__ __launch_bounds__(64) void fc(const float* __restrict__ sums,
                                         const int* __restrict__ batch,
                                         const float* __restrict__ fcW,
                                         const float* __restrict__ fcb,
                                         float* __restrict__ out) {
    __shared__ float mean[64];
    int g = blockIdx.x;
    int lo = 0, hi = N_NODES;
    while (lo < hi) { int mid = (lo + hi) >> 1; if (batch[mid] < g) lo = mid + 1; else hi = mid; }
    int start = lo;
    hi = N_NODES;
    while (lo < hi) { int mid = (lo + hi) >> 1; if (batch[mid] < g + 1) lo = mid + 1; else hi = mid; }
    int end = lo;
    float inv = 1.0f / fmaxf((float)(end - start), 1.0f);
    mean[threadIdx.x] = sums[g * DIM + threadIdx.x] * inv;   // same-wave LDS, no barrier
    if (threadIdx.x < ODIM) {
        int jj = threadIdx.x;
        float a = fcb[jj];
#pragma unroll
        for (int k = 0; k < DIM; ++k) a = fmaf(mean[k], fcW[k * ODIM + jj], a);
        out[g * ODIM + jj] = a;
    }
}

extern "C" void kernel_launch(void* const* d_in, const int* in_sizes, int n_in,
                              void* d_out, int out_size, void* d_ws, size_t ws_size,
                              hipStream_t stream) {
    const float* x    = (const float*)d_in[0];
    const float* W1   = (const float*)d_in[1];
    const float* b1   = (const float*)d_in[2];
    const float* W2   = (const float*)d_in[3];
    const float* b2   = (const float*)d_in[4];
    const float* fcW  = (const float*)d_in[5];
    const float* fcb  = (const float*)d_in[6];
    const int*   eidx = (const int*)d_in[7];
    const int*   batch= (const int*)d_in[8];
    const int* esrc = eidx;
    const int* edst = eidx + N_EDGES;
    float* out = (float*)d_out;

    char* ws = (char*)d_ws;
    size_t o = 0;
    auto alloc = [&](size_t bytes) {
        void* p = ws + o;
        o += (bytes + 255) & ~(size_t)255;
        return p;
    };
    __hip_bfloat16* bf1 = (__hip_bfloat16*)alloc((size_t)N_NODES * DIM * 2);
    __hip_bfloat16* bf2 = (__hip_bfloat16*)alloc((size_t)N_NODES * DIM * 2);
    int*   cnt      = (int*)  alloc((size_t)N_NODES * 4);
    int*   off      = (int*)  alloc((size_t)(N_NODES + 1) * 4);
    int*   cursor   = (int*)  alloc((size_t)N_NODES * 4);
    float* inv_sqrt = (float*)alloc((size_t)N_NODES * 4);
    float* invdeg   = (float*)alloc((size_t)N_NODES * 4);
    unsigned int* edges = (unsigned int*)alloc((size_t)N_EDGES * 4);
    int*   blocksum = (int*)  alloc((size_t)SCAN_NB * 4);
    float* sums     = (float*)alloc((size_t)N_GRAPHS * DIM * 4);

    hipMemsetAsync(cnt,  0, (size_t)N_NODES * 4, stream);
    hipMemsetAsync(sums, 0, (size_t)N_GRAPHS * DIM * 4, stream);

    count_deg<<<(N_EDGES + 255) / 256, 256, 0, stream>>>(edst, cnt);
    scan_p1<<<SCAN_NB, 256, 0, stream>>>(cnt, blocksum);
    scan_p3<<<SCAN_NB, 256, 0, stream>>>(cnt, blocksum, off, cursor, inv_sqrt, invdeg);
    scatter_edges<<<((N_EDGES + 255) / 256) * NXCD, 256, 0, stream>>>(esrc, edst, inv_sqrt, cursor, edges);

    gemm64<<<(N_NODES + 31) / 32, 256, 0, stream>>>(x, W1, bf1, N_NODES);
    agg_gemm<<<N_NODES / 16, 256, 0, stream>>>(bf1, off, edges, invdeg, b1, W2, bf2);
    agg_pool<<<N_NODES / 16, 256, 0, stream>>>(bf2, off, edges, invdeg, b2, batch, sums);

    fc<<<N_GRAPHS, 64, 0, stream>>>(sums, batch, fcW, fcb, out);
}

// Round 18
// 253.705 us; speedup vs baseline: 1.0566x; 1.0566x over previous
//
#include <hip/hip_runtime.h>
#include <hip/hip_bf16.h>
#include <hip/hip_fp16.h>

#define N_NODES 50000
#define N_EDGES 800000
#define DIM 64
#define ODIM 32
#define N_GRAPHS 512
#define SCAN_NB ((N_NODES + 255) / 256)   // 196
#define NXCD 8
#define DST_RANGE ((N_NODES + NXCD - 1) / NXCD)   // 6250

__device__ __forceinline__ float bflo(unsigned int u) { return __uint_as_float(u << 16); }
__device__ __forceinline__ float bfhi(unsigned int u) { return __uint_as_float(u & 0xffff0000u); }
__device__ __forceinline__ float h16tof(unsigned int hbits) {
    return __half2float(__ushort_as_half((unsigned short)hbits));
}

// ---- graph prep: counting-sort edges by dst into CSR ----

__global__ void count_deg(const int* __restrict__ dst, int* __restrict__ cnt) {
    int e = blockIdx.x * blockDim.x + threadIdx.x;
    if (e < N_EDGES) atomicAdd(&cnt[__builtin_nontemporal_load(&dst[e])], 1);
}

// ---- 2-phase exclusive scan over cnt[N_NODES] ----

__global__ __launch_bounds__(256) void scan_p1(const int* __restrict__ cnt,
                                               int* __restrict__ blocksum) {
    __shared__ int ws[4];
    int i = blockIdx.x * 256 + threadIdx.x;
    int v = (i < N_NODES) ? cnt[i] : 0;
    for (int d = 32; d > 0; d >>= 1) v += __shfl_down(v, d, 64);
    int lane = threadIdx.x & 63, wid = threadIdx.x >> 6;
    if (lane == 0) ws[wid] = v;
    __syncthreads();
    if (threadIdx.x == 0) blocksum[blockIdx.x] = ws[0] + ws[1] + ws[2] + ws[3];
}

__global__ __launch_bounds__(256) void scan_p3(const int* __restrict__ cnt,
                                               const int* __restrict__ blocksum,
                                               int* __restrict__ off,
                                               int* __restrict__ cursor,
                                               float* __restrict__ inv_sqrt,
                                               float* __restrict__ invdeg) {
    __shared__ int wtot[4];
    __shared__ int bb[SCAN_NB + 1];
    {
        int t = threadIdx.x;
        int v = (t < SCAN_NB) ? blocksum[t] : 0;
        int lane = t & 63, wid = t >> 6;
        int incl = v;
        for (int d = 1; d < 64; d <<= 1) {
            int u = __shfl_up(incl, d, 64);
            if (lane >= d) incl += u;
        }
        if (lane == 63) wtot[wid] = incl;
        __syncthreads();
        int base = 0;
        for (int w = 0; w < wid; ++w) base += wtot[w];
        incl += base;
        if (t <= SCAN_NB) bb[t] = incl - v;   // exclusive; bb[SCAN_NB] = total
        __syncthreads();
    }
    if (blockIdx.x == 0 && threadIdx.x == 0) off[N_NODES] = bb[SCAN_NB];
    __syncthreads();

    int i = blockIdx.x * 256 + threadIdx.x;
    int v = (i < N_NODES) ? cnt[i] : 0;
    int lane = threadIdx.x & 63, wid = threadIdx.x >> 6;
    int incl = v;
    for (int d = 1; d < 64; d <<= 1) {
        int u = __shfl_up(incl, d, 64);
        if (lane >= d) incl += u;
    }
    __syncthreads();
    if (lane == 63) wtot[wid] = incl;
    __syncthreads();
    int base = bb[blockIdx.x];
    for (int w = 0; w < wid; ++w) base += wtot[w];
    int excl = base + incl - v;
    if (i < N_NODES) {
        off[i] = excl; cursor[i] = excl;
        float d = (float)(v + 1);   // self-loop
        inv_sqrt[i] = rsqrtf(d);
        invdeg[i]   = 1.0f / d;
    }
}

// XCD-partitioned scatter: block = (chunk, range); blockIdx%8 -> XCD round-robin.
// Edge record packed to 4B: src (u16) | half(w) << 16.
__global__ void scatter_edges(const int* __restrict__ src, const int* __restrict__ dst,
                              const float* __restrict__ inv_sqrt,
                              int* __restrict__ cursor,
                              unsigned int* __restrict__ edges) {
    int chunk = blockIdx.x >> 3;
    int range = blockIdx.x & 7;
    int e = chunk * 256 + threadIdx.x;
    if (e >= N_EDGES) return;
    int d = dst[e];
    int lo = range * DST_RANGE;
    if ((unsigned)(d - lo) < (unsigned)DST_RANGE) {
        int s = src[e];
        int pos = atomicAdd(&cursor[d], 1);
        float w = inv_sqrt[s] * inv_sqrt[d];
        unsigned short hw = __half_as_ushort(__float2half(w));
        edges[pos] = (unsigned int)s | ((unsigned int)hw << 16);
    }
}

// ---- half-wave packed merged-stream gather for 4 consecutive nodes ----
// H viewed as uint rows of 32 (2 bf16 per uint). Lane = (m=j&31, h=j>>5):
// half h handles edges k+2i+h; one uint gather serves 2 edges/wave-inst.
// 4B edge records: src = rec & 0xffff, w = half(rec >> 16).
// Caller combines halves via shfl_xor(32).
__device__ __forceinline__ void gather4_packed(
    const unsigned int* __restrict__ H2,
    const unsigned int* __restrict__ edges,
    int e0, int b1, int b2, int b3, int e4, int m, int h,
    float (&aLo)[4], float (&aHi)[4])
{
    int k = e0;
    int B = (e4 - e0) >> 3;

    unsigned int Ec[4]; unsigned int Uc[4];
    unsigned int En[4];

    auto ld4 = [&](unsigned int* E, int kb) {
#pragma unroll
        for (int i = 0; i < 4; ++i) E[i] = edges[kb + 2 * i + h];
    };
    auto gt4 = [&](unsigned int* U, const unsigned int* E) {
#pragma unroll
        for (int i = 0; i < 4; ++i)
            U[i] = H2[(size_t)(E[i] & 0xffffu) * 32 + m];
    };
    auto consume = [&](const unsigned int* E, const unsigned int* U, int kb) {
        int selA = (kb >= b1) + (kb >= b2) + (kb >= b3);
        int selB = (kb + 7 >= b1) + (kb + 7 >= b2) + (kb + 7 >= b3);
        if (selA == selB) {                 // whole batch in one node (common)
            float sLo = 0.f, sHi = 0.f;
#pragma unroll
            for (int i = 0; i < 4; ++i) {
                float w = h16tof(E[i] >> 16);
                sLo = fmaf(bflo(U[i]), w, sLo);
                sHi = fmaf(bfhi(U[i]), w, sHi);
            }
            if      (selA == 0) { aLo[0] += sLo; aHi[0] += sHi; }
            else if (selA == 1) { aLo[1] += sLo; aHi[1] += sHi; }
            else if (selA == 2) { aLo[2] += sLo; aHi[2] += sHi; }
            else                { aLo[3] += sLo; aHi[3] += sHi; }
        } else {                            // boundary batch: per-edge select
#pragma unroll
            for (int i = 0; i < 4; ++i) {
                int kk = kb + 2 * i + h;
                float w = h16tof(E[i] >> 16);
                float pLo = bflo(U[i]) * w;
                float pHi = bfhi(U[i]) * w;
                int sel = (kk >= b1) + (kk >= b2) + (kk >= b3);
                aLo[0] += (sel == 0) ? pLo : 0.f;  aHi[0] += (sel == 0) ? pHi : 0.f;
                aLo[1] += (sel == 1) ? pLo : 0.f;  aHi[1] += (sel == 1) ? pHi : 0.f;
                aLo[2] += (sel == 2) ? pLo : 0.f;  aHi[2] += (sel == 2) ? pHi : 0.f;
                aLo[3] += (sel == 3) ? pLo : 0.f;  aHi[3] += (sel == 3) ? pHi : 0.f;
            }
        }
    };

    if (B >= 2) {
        ld4(Ec, k);
        gt4(Uc, Ec);
        ld4(En, k + 8);
        for (int b = 0; b < B - 2; ++b) {
            unsigned int Un[4];
            gt4(Un, En);          // gathers batch b+1 in flight
            unsigned int Ef[4];
            ld4(Ef, k + 16);      // edge loads batch b+2 in flight
            consume(Ec, Uc, k);   // waits only on batch b gathers
#pragma unroll
            for (int i = 0; i < 4; ++i) { Ec[i] = En[i]; Uc[i] = Un[i]; En[i] = Ef[i]; }
            k += 8;
        }
        {
            unsigned int Un[4];
            gt4(Un, En);
            consume(Ec, Uc, k);
#pragma unroll
            for (int i = 0; i < 4; ++i) { Ec[i] = En[i]; Uc[i] = Un[i]; }
            k += 8;
            consume(Ec, Uc, k);
            k += 8;
        }
    } else if (B == 1) {
        ld4(Ec, k); gt4(Uc, Ec); consume(Ec, Uc, k); k += 8;
    }
    for (; k < e4; ++k) {
        if ((k & 1) == h) {       // split tail edges between halves
            unsigned int e = edges[k];
            unsigned int u = H2[(size_t)(e & 0xffffu) * 32 + m];
            float w = h16tof(e >> 16);
            float pLo = bflo(u) * w;
            float pHi = bfhi(u) * w;
            int sel = (k >= b1) + (k >= b2) + (k >= b3);
            aLo[0] += (sel == 0) ? pLo : 0.f;  aHi[0] += (sel == 0) ? pHi : 0.f;
            aLo[1] += (sel == 1) ? pLo : 0.f;  aHi[1] += (sel == 1) ? pHi : 0.f;
            aLo[2] += (sel == 2) ? pLo : 0.f;  aHi[2] += (sel == 2) ? pHi : 0.f;
            aLo[3] += (sel == 3) ? pLo : 0.f;  aHi[3] += (sel == 3) ? pHi : 0.f;
        }
    }
}

// ---- h = X @ W  (N x 64 @ 64 x 64); bf16 output only ----
// W in NATURAL [k][j] layout in LDS (2-way alias only: free).

__global__ __launch_bounds__(256) void gemm64(const float* __restrict__ X,
                                              const float* __restrict__ W,
                                              __hip_bfloat16* __restrict__ Ybf,
                                              int nrows) {
    __shared__ float Ws[64 * 64];
    for (int i = threadIdx.x; i < 64 * 64; i += 256) Ws[i] = W[i];
    __syncthreads();
    int wave = threadIdx.x >> 6;
    int j    = threadIdx.x & 63;
    int row0 = (blockIdx.x * 4 + wave) * 8;
    if (row0 >= nrows) return;
    float acc[8] = {0,0,0,0,0,0,0,0};
    const float* x0 = X + (size_t)row0 * DIM;   // wave-uniform
    int nr = (row0 + 8 <= nrows) ? 8 : (nrows - row0);
    if (nr == 8) {
#pragma unroll
        for (int k4 = 0; k4 < 16; ++k4) {
            float w0 = Ws[(4 * k4 + 0) * 64 + j];
            float w1 = Ws[(4 * k4 + 1) * 64 + j];
            float w2 = Ws[(4 * k4 + 2) * 64 + j];
            float w3 = Ws[(4 * k4 + 3) * 64 + j];
#pragma unroll
            for (int r = 0; r < 8; ++r) {
                float4 x4 = *(const float4*)&x0[r * DIM + k4 * 4];
                acc[r] = fmaf(x4.x, w0, acc[r]);
                acc[r] = fmaf(x4.y, w1, acc[r]);
                acc[r] = fmaf(x4.z, w2, acc[r]);
                acc[r] = fmaf(x4.w, w3, acc[r]);
            }
        }
    } else {
        for (int k4 = 0; k4 < 16; ++k4) {
            float w0 = Ws[(4 * k4 + 0) * 64 + j];
            float w1 = Ws[(4 * k4 + 1) * 64 + j];
            float w2 = Ws[(4 * k4 + 2) * 64 + j];
            float w3 = Ws[(4 * k4 + 3) * 64 + j];
            for (int r = 0; r < nr; ++r) {
                float4 x4 = *(const float4*)&x0[r * DIM + k4 * 4];
                acc[r] = fmaf(x4.x, w0, acc[r]);
                acc[r] = fmaf(x4.y, w1, acc[r]);
                acc[r] = fmaf(x4.z, w2, acc[r]);
                acc[r] = fmaf(x4.w, w3, acc[r]);
            }
        }
    }
    for (int r = 0; r < nr; ++r)
        Ybf[(size_t)(row0 + r) * DIM + j] = __float2bfloat16(acc[r]);
}

// ---- fused: layer-1 aggregate (+bias1, relu) THEN layer-2 gemm (@W2) ----
// Packed gather; halves combined via shfl_xor; rowbuf written by half 0.

__global__ __launch_bounds__(256) void agg_gemm(const __hip_bfloat16* __restrict__ Hbf,
                                                const int* __restrict__ off,
                                                const unsigned int* __restrict__ edges,
                                                const float* __restrict__ invdeg,
                                                const float* __restrict__ bias,
                                                const float* __restrict__ W2,
                                                __hip_bfloat16* __restrict__ Ybf2) {
    __shared__ float Ws[64 * 64];
    __shared__ float rowbuf[4][4][64];   // [wave][r][j]
    for (int i = threadIdx.x; i < 64 * 64; i += 256) Ws[i] = W2[i];
    __syncthreads();
    const unsigned int* H2 = (const unsigned int*)Hbf;
    int wave = threadIdx.x >> 6;
    int j    = threadIdx.x & 63;
    int m = j & 31, h = j >> 5;
    int n0   = (blockIdx.x * 4 + wave) * 4;   // N_NODES = 16*3125: exact
    int e0 = off[n0], b1v = off[n0 + 1], b2v = off[n0 + 2], b3v = off[n0 + 3], e4 = off[n0 + 4];
    float aLo[4] = {0.f, 0.f, 0.f, 0.f};
    float aHi[4] = {0.f, 0.f, 0.f, 0.f};
    gather4_packed(H2, edges, e0, b1v, b2v, b3v, e4, m, h, aLo, aHi);
    float bLo = bias[2 * m], bHi = bias[2 * m + 1];
#pragma unroll
    for (int r = 0; r < 4; ++r) {
        aLo[r] += __shfl_xor(aLo[r], 32);
        aHi[r] += __shfl_xor(aHi[r], 32);
        unsigned int u = H2[(size_t)(n0 + r) * 32 + m];   // self row
        float iv = invdeg[n0 + r];
        float vLo = fmaf(bflo(u), iv, aLo[r]) + bLo;
        float vHi = fmaf(bfhi(u), iv, aHi[r]) + bHi;
        if (h == 0) {
            rowbuf[wave][r][2 * m]     = fmaxf(vLo, 0.f);
            rowbuf[wave][r][2 * m + 1] = fmaxf(vHi, 0.f);
        }
    }
    // same-wave LDS write->read: compiler inserts lgkmcnt wait; no barrier needed
    float acc2[4] = {0.f, 0.f, 0.f, 0.f};
#pragma unroll
    for (int k4 = 0; k4 < 16; ++k4) {
        float w0 = Ws[(4 * k4 + 0) * 64 + j];
        float w1 = Ws[(4 * k4 + 1) * 64 + j];
        float w2 = Ws[(4 * k4 + 2) * 64 + j];
        float w3 = Ws[(4 * k4 + 3) * 64 + j];
#pragma unroll
        for (int r = 0; r < 4; ++r) {
            float4 h4 = *(const float4*)&rowbuf[wave][r][k4 * 4];  // broadcast: free
            acc2[r] = fmaf(h4.x, w0, acc2[r]);
            acc2[r] = fmaf(h4.y, w1, acc2[r]);
            acc2[r] = fmaf(h4.z, w2, acc2[r]);
            acc2[r] = fmaf(h4.w, w3, acc2[r]);
        }
    }
#pragma unroll
    for (int r = 0; r < 4; ++r)
        Ybf2[(size_t)(n0 + r) * DIM + j] = __float2bfloat16(acc2[r]);
}

// ---- layer-2 aggregate (+bias2, relu) fused with mean-pool accumulation ----
// Packed gather; atomics from half 0 only (2 per lane).

__global__ __launch_bounds__(256) void agg_pool(const __hip_bfloat16* __restrict__ Hbf,
                                                const int* __restrict__ off,
                                                const unsigned int* __restrict__ edges,
                                                const float* __restrict__ invdeg,
                                                const float* __restrict__ bias,
                                                const int* __restrict__ batch,
                                                float* __restrict__ sums) {
    const unsigned int* H2 = (const unsigned int*)Hbf;
    int wave = threadIdx.x >> 6;
    int j    = threadIdx.x & 63;
    int m = j & 31, h = j >> 5;
    int n0   = (blockIdx.x * 4 + wave) * 4;   // exact
    int e0 = off[n0], b1v = off[n0 + 1], b2v = off[n0 + 2], b3v = off[n0 + 3], e4 = off[n0 + 4];
    float aLo[4] = {0.f, 0.f, 0.f, 0.f};
    float aHi[4] = {0.f, 0.f, 0.f, 0.f};
    gather4_packed(H2, edges, e0, b1v, b2v, b3v, e4, m, h, aLo, aHi);
    float bLo = bias[2 * m], bHi = bias[2 * m + 1];
    float vLo[4], vHi[4];
#pragma unroll
    for (int r = 0; r < 4; ++r) {
        aLo[r] += __shfl_xor(aLo[r], 32);
        aHi[r] += __shfl_xor(aHi[r], 32);
        unsigned int u = H2[(size_t)(n0 + r) * 32 + m];
        float iv = invdeg[n0 + r];
        vLo[r] = fmaxf(fmaf(bflo(u), iv, aLo[r]) + bLo, 0.f);
        vHi[r] = fmaxf(fmaf(bfhi(u), iv, aHi[r]) + bHi, 0.f);
    }
    if (h == 0) {
        int g0 = batch[n0], g3 = batch[n0 + 3];
        if (g0 == g3) {
            atomicAdd(&sums[g0 * DIM + 2 * m],     (vLo[0] + vLo[1]) + (vLo[2] + vLo[3]));
            atomicAdd(&sums[g0 * DIM + 2 * m + 1], (vHi[0] + vHi[1]) + (vHi[2] + vHi[3]));
        } else {
#pragma unroll
            for (int r = 0; r < 4; ++r) {
                int g = batch[n0 + r];
                atomicAdd(&sums[g * DIM + 2 * m],     vLo[r]);
                atomicAdd(&sums[g * DIM + 2 * m + 1], vHi[r]);
            }
        }
    }
}

// ---- FC over pooled means: one 64-thread block per graph ----

__global__ __launch_bounds__(64) void fc(const float* __restrict__ sums,
                                         const int* __restrict__ batch,
                                         const float* __restrict__ fcW,
                                         const float* __restrict__ fcb,
                                         float* __restrict__ out) {
    __shared__ float mean[64];
    int g = blockIdx.x;
    int lo = 0, hi = N_NODES;
    while (lo < hi) { int mid = (lo + hi) >> 1; if (batch[mid] < g) lo = mid + 1; else hi = mid; }
    int start = lo;
    hi = N_NODES;
    while (lo < hi) { int mid = (lo + hi) >> 1; if (batch[mid] < g + 1) lo = mid + 1; else hi = mid; }
    int end = lo;
    float inv = 1.0f / fmaxf((float)(end - start), 1.0f);
    mean[threadIdx.x] = sums[g * DIM + threadIdx.x] * inv;   // same-wave LDS, no barrier
    if (threadIdx.x < ODIM) {
        int jj = threadIdx.x;
        float a = fcb[jj];
#pragma unroll
        for (int k = 0; k < DIM; ++k) a = fmaf(mean[k], fcW[k * ODIM + jj], a);
        out[g * ODIM + jj] = a;
    }
}

extern "C" void kernel_launch(void* const* d_in, const int* in_sizes, int n_in,
                              void* d_out, int out_size, void* d_ws, size_t ws_size,
                              hipStream_t stream) {
    const float* x    = (const float*)d_in[0];
    const float* W1   = (const float*)d_in[1];
    const float* b1   = (const float*)d_in[2];
    const float* W2   = (const float*)d_in[3];
    const float* b2   = (const float*)d_in[4];
    const float* fcW  = (const float*)d_in[5];
    const float* fcb  = (const float*)d_in[6];
    const int*   eidx = (const int*)d_in[7];
    const int*   batch= (const int*)d_in[8];
    const int* esrc = eidx;
    const int* edst = eidx + N_EDGES;
    float* out = (float*)d_out;

    char* ws = (char*)d_ws;
    size_t o = 0;
    auto alloc = [&](size_t bytes) {
        void* p = ws + o;
        o += (bytes + 255) & ~(size_t)255;
        return p;
    };
    __hip_bfloat16* bf1 = (__hip_bfloat16*)alloc((size_t)N_NODES * DIM * 2);
    __hip_bfloat16* bf2 = (__hip_bfloat16*)alloc((size_t)N_NODES * DIM * 2);
    int*   cnt      = (int*)  alloc((size_t)N_NODES * 4);
    int*   off      = (int*)  alloc((size_t)(N_NODES + 1) * 4);
    int*   cursor   = (int*)  alloc((size_t)N_NODES * 4);
    float* inv_sqrt = (float*)alloc((size_t)N_NODES * 4);
    float* invdeg   = (float*)alloc((size_t)N_NODES * 4);
    unsigned int* edges = (unsigned int*)alloc((size_t)N_EDGES * 4);
    int*   blocksum = (int*)  alloc((size_t)SCAN_NB * 4);
    float* sums     = (float*)alloc((size_t)N_GRAPHS * DIM * 4);

    hipMemsetAsync(cnt,  0, (size_t)N_NODES * 4, stream);
    hipMemsetAsync(sums, 0, (size_t)N_GRAPHS * DIM * 4, stream);

    count_deg<<<(N_EDGES + 255) / 256, 256, 0, stream>>>(edst, cnt);
    scan_p1<<<SCAN_NB, 256, 0, stream>>>(cnt, blocksum);
    scan_p3<<<SCAN_NB, 256, 0, stream>>>(cnt, blocksum, off, cursor, inv_sqrt, invdeg);
    scatter_edges<<<((N_EDGES + 255) / 256) * NXCD, 256, 0, stream>>>(esrc, edst, inv_sqrt, cursor, edges);

    gemm64<<<(N_NODES + 31) / 32, 256, 0, stream>>>(x, W1, bf1, N_NODES);
    agg_gemm<<<N_NODES / 16, 256, 0, stream>>>(bf1, off, edges, invdeg, b1, W2, bf2);
    agg_pool<<<N_NODES / 16, 256, 0, stream>>>(bf2, off, edges, invdeg, b2, batch, sums);

    fc<<<N_GRAPHS, 64, 0, stream>>>(sums, batch, fcW, fcb, out);
}